// Round 8
// baseline (258.470 us; speedup 1.0000x reference)
//
#include <hip/hip_runtime.h>
#include <hip/hip_fp16.h>

#define S_LEN    1024
#define B_SZ     8
#define D_IN     64
#define D_OUT    96
#define NB       8
#define NE       (D_OUT * D_OUT)          // 9216
#define CHUNK    8                        // s-steps per recurrence chain
#define NCHUNK   (S_LEN / CHUNK)          // 128
#define NT_P     256
#define NWBLK    (NCHUNK * (NE / NT_P))   // 4608 W-recurrence blocks
#define GROWS    32                       // (b,s)-rows per GEMM block
#define NROWS    (B_SZ * S_LEN)           // 8192
#define NGBLK    (NROWS / GROWS)          // 256 GEMM blocks
#define WPITCH   104                      // halves; 52 words -> b128 rows tile all 32 banks
#define NT_C     512                      // 8 waves = 8 batch rows
#define SPAD     100
#define XPAD     68

__device__ __forceinline__ float cos_rev(float v) {   // cos(2*pi*v), v in revolutions
    v -= floorf(v);
    return __builtin_amdgcn_cosf(v);
}

// ---------------- Producer: W1/W2 recurrence + layer-1 GEMMs, one launch ----------------
__global__ void __launch_bounds__(NT_P)
producer(const float* __restrict__ P1, const float* __restrict__ P2,
         const float* __restrict__ seq, const float* __restrict__ M1,
         const float* __restrict__ Wres1,
         __half* __restrict__ W1, __half* __restrict__ W2,
         float* __restrict__ XT, float* __restrict__ RS) {
    const int tid = threadIdx.x;
    if (blockIdx.x < NWBLK) {
        // --- W part (r6-proven): c(s+1) = 2cos(2pi/p)c(s) - c(s-1) ---
        const int c  = blockIdx.x / (NE / NT_P);
        const int eb = blockIdx.x % (NE / NT_P);
        const int e  = eb * NT_P + tid;
        const int s0 = c * CHUNK;
        const float s0f = (float)s0;

        float p1l[NB], p2l[NB];
        *(float4*)&p1l[0] = *(const float4*)(P1 + e * NB);
        *(float4*)&p1l[4] = *(const float4*)(P1 + e * NB + 4);
        *(float4*)&p2l[0] = *(const float4*)(P2 + e * NB);
        *(float4*)&p2l[4] = *(const float4*)(P2 + e * NB + 4);

        float cc[NB], cp[NB], kk[NB];
        #pragma unroll
        for (int g = 0; g < NB; ++g) {
            const float inv = __builtin_amdgcn_rcpf((float)(e * NB + 2 + g));
            cc[g] = cos_rev(s0f * inv);
            cp[g] = cos_rev((s0f - 1.0f) * inv);
            kk[g] = 2.0f * __builtin_amdgcn_cosf(inv);   // inv <= 0.5 rev
        }
        #pragma unroll
        for (int s = s0; s < s0 + CHUNK; ++s) {
            float a1 = 0.0f, a2 = 0.0f;
            #pragma unroll
            for (int g = 0; g < NB; ++g) {
                a1 = fmaf(p1l[g], cc[g], a1);
                a2 = fmaf(p2l[g], cc[g], a2);
            }
            W1[s * NE + e] = __float2half(a1);
            W2[s * NE + e] = __float2half(a2);
            #pragma unroll
            for (int g = 0; g < NB; ++g) {
                float cn = fmaf(kk[g], cc[g], -cp[g]);
                cp[g] = cc[g];
                cc[g] = cn;
            }
        }
    } else {
        // --- layer-1 GEMM part: xt1 = seq@M1^T, res1 = seq@Wres1^T ---
        __shared__ __align__(16) float xs[GROWS * XPAD];
        const int r0 = (blockIdx.x - NWBLK) * GROWS;
        for (int cdx = tid; cdx < GROWS * (D_IN / 4); cdx += NT_P) {
            int rr = cdx >> 4, q = cdx & 15;
            *(float4*)(xs + rr * XPAD + q * 4) =
                *(const float4*)(seq + (size_t)(r0 + rr) * D_IN + q * 4);
        }
        __syncthreads();
        const int rr = tid >> 3;     // 0..31 row within tile
        const int ig = tid & 7;      // i-group
        const float* xr = xs + rr * XPAD;
        #pragma unroll
        for (int ii = 0; ii < 12; ++ii) {
            const int i = ig + ii * 8;          // 8 lanes share each M row
            const float4* m = (const float4*)(M1 + i * D_IN);
            const float4* w = (const float4*)(Wres1 + i * D_IN);
            float at = 0.0f, ar = 0.0f;
            #pragma unroll
            for (int k = 0; k < D_IN / 4; ++k) {
                float4 mv = m[k], rv = w[k];
                float4 xv = *(const float4*)(xr + 4 * k);
                at = fmaf(mv.x, xv.x, fmaf(mv.y, xv.y, fmaf(mv.z, xv.z, fmaf(mv.w, xv.w, at))));
                ar = fmaf(rv.x, xv.x, fmaf(rv.y, xv.y, fmaf(rv.z, xv.z, fmaf(rv.w, xv.w, ar))));
            }
            XT[(size_t)(r0 + rr) * D_OUT + i] = at;
            RS[(size_t)(r0 + rr) * D_OUT + i] = ar;
        }
    }
}

// ---------------- consumer helpers ----------------
// dot over 96: f16 W row (LDS, conflict-free b128) x f32 x-row (LDS broadcast)
__device__ __forceinline__ float nkdot(const __half* __restrict__ wrow,
                                       const float* __restrict__ xr) {
    float acc = 0.0f;
    #pragma unroll
    for (int j = 0; j < 12; ++j) {
        float4 raw = *(const float4*)(wrow + 8 * j);
        const __half2* hp = (const __half2*)&raw;
        float2 c0 = __half22float2(hp[0]);
        float2 c1 = __half22float2(hp[1]);
        float2 c2 = __half22float2(hp[2]);
        float2 c3 = __half22float2(hp[3]);
        float4 x0 = *(const float4*)(xr + 8 * j);
        float4 x1 = *(const float4*)(xr + 8 * j + 4);
        acc = fmaf(c0.x, x0.x, acc); acc = fmaf(c0.y, x0.y, acc);
        acc = fmaf(c1.x, x0.z, acc); acc = fmaf(c1.y, x0.w, acc);
        acc = fmaf(c2.x, x1.x, acc); acc = fmaf(c2.y, x1.y, acc);
        acc = fmaf(c3.x, x1.z, acc); acc = fmaf(c3.y, x1.w, acc);
    }
    return acc;
}

// dot over 96: f32 global M row (L1/L2-cached gather) x f32 x-row (LDS broadcast)
__device__ __forceinline__ float gemv96(const float* __restrict__ mrow,
                                        const float* __restrict__ xr) {
    float acc = 0.0f;
    #pragma unroll
    for (int k = 0; k < 24; ++k) {
        float4 mv = *(const float4*)(mrow + 4 * k);
        float4 xv = *(const float4*)(xr + 4 * k);
        acc = fmaf(mv.x, xv.x, fmaf(mv.y, xv.y, fmaf(mv.z, xv.z, fmaf(mv.w, xv.w, acc))));
    }
    return acc;
}

// ---------------- Consumer: ONE barrier, one wave64 per batch row ----------------
__global__ void __launch_bounds__(NT_C, 4)
consumer(const float* __restrict__ XT, const float* __restrict__ RS,
         const float* __restrict__ M2,
         const float* __restrict__ g1, const float* __restrict__ b1,
         const float* __restrict__ g2, const float* __restrict__ b2,
         const __half* __restrict__ W1g, const __half* __restrict__ W2g,
         float* __restrict__ out) {
    __shared__ __align__(16) __half wh1[D_OUT * WPITCH];   // 19968 B
    __shared__ __align__(16) __half wh2[D_OUT * WPITCH];   // 19968 B
    __shared__ __align__(16) float  xbuf[B_SZ * SPAD];     // 3200 B -> 43136 total, 3 blk/CU

    const int s    = blockIdx.x;
    const int tid  = threadIdx.x;
    const int b    = tid >> 6;
    const int lane = tid & 63;
    const bool lo  = (lane < 32);

    // cooperative stage of BOTH W slices (the only cross-wave data)
    {
        const __half* W1s = W1g + (size_t)s * NE;
        const __half* W2s = W2g + (size_t)s * NE;
        for (int c = tid; c < NE / 8; c += NT_C) {
            int i = c / 12, j = (c % 12) * 8;
            *(float4*)(wh1 + i * WPITCH + j) = *(const float4*)(W1s + c * 8);
        }
        for (int c = tid; c < NE / 8; c += NT_C) {
            int i = c / 12, j = (c % 12) * 8;
            *(float4*)(wh2 + i * WPITCH + j) = *(const float4*)(W2s + c * 8);
        }
    }

    // per-wave inputs: lane l owns features {l, 64+l(<96)} — coalesced row reads
    const size_t r = (size_t)b * S_LEN + s;
    float xt0 = XT[r * D_OUT + lane];
    float rs0 = RS[r * D_OUT + lane];
    float xt1 = 0.0f, rs1 = 0.0f;
    if (lo) {
        xt1 = XT[r * D_OUT + 64 + lane];
        rs1 = RS[r * D_OUT + 64 + lane];
    }
    __syncthreads();   // B1 — the ONLY barrier

    float* xr = xbuf + b * SPAD;   // per-wave private row; wave-lockstep orders LDS w->r

    // ---- LN1 (in-wave reduction over the 96 features) ----
    {
        float sum = xt0 + xt1;
        float sq  = fmaf(xt0, xt0, xt1 * xt1);
        #pragma unroll
        for (int off = 32; off > 0; off >>= 1) {
            sum += __shfl_down(sum, off, 64);
            sq  += __shfl_down(sq,  off, 64);
        }
        sum = __shfl(sum, 0, 64);
        sq  = __shfl(sq,  0, 64);
        const float mu  = sum * (1.0f / 96.0f);
        const float var = fmaf(sq, 1.0f / 96.0f, -(mu * mu));
        const float rst = rsqrtf(var + 1e-5f);
        float xn0 = fmaf((xt0 - mu) * rst, g1[lane], b1[lane]);
        xr[lane] = xn0;
        if (lo) {
            float xn1 = fmaf((xt1 - mu) * rst, g1[64 + lane], b1[64 + lane]);
            xr[64 + lane] = xn1;
        }
    }

    // ---- Nk1 + residual ----
    float x10 = rs0 + nkdot(wh1 + lane * WPITCH, xr);
    float x11 = 0.0f;
    if (lo) x11 = rs1 + nkdot(wh1 + (64 + lane) * WPITCH, xr);

    // publish x1 for the j-broadcasts (program order per wave: all wh1 reads done)
    xr[lane] = x10;
    if (lo) xr[64 + lane] = x11;

    // ---- layer-2 GEMV: xt2_i = M2[i,:] . x1 ----
    float t0 = gemv96(M2 + lane * D_OUT, xr);
    float t1 = 0.0f;
    if (lo) t1 = gemv96(M2 + (64 + lane) * D_OUT, xr);

    // ---- LN2 ----
    {
        float sum = t0 + t1;
        float sq  = fmaf(t0, t0, t1 * t1);
        #pragma unroll
        for (int off = 32; off > 0; off >>= 1) {
            sum += __shfl_down(sum, off, 64);
            sq  += __shfl_down(sq,  off, 64);
        }
        sum = __shfl(sum, 0, 64);
        sq  = __shfl(sq,  0, 64);
        const float mu  = sum * (1.0f / 96.0f);
        const float var = fmaf(sq, 1.0f / 96.0f, -(mu * mu));
        const float rst = rsqrtf(var + 1e-5f);
        float xn0 = fmaf((t0 - mu) * rst, g2[lane], b2[lane]);
        xr[lane] = xn0;
        if (lo) {
            float xn1 = fmaf((t1 - mu) * rst, g2[64 + lane], b2[64 + lane]);
            xr[64 + lane] = xn1;
        }
    }

    // ---- Nk2 + identity residual -> out (coalesced) ----
    float o0 = nkdot(wh2 + lane * WPITCH, xr) + x10;
    out[r * D_OUT + lane] = o0;
    if (lo) {
        float o1 = nkdot(wh2 + (64 + lane) * WPITCH, xr) + x11;
        out[r * D_OUT + 64 + lane] = o1;
    }
}

// ---------------- Fallback (round-1 proven kernel) if ws too small ----------------
__global__ void __launch_bounds__(NT_P)
hier_fallback(const float* __restrict__ seq,  const float* __restrict__ M1,
              const float* __restrict__ P1,   const float* __restrict__ Wres1,
              const float* __restrict__ g1,   const float* __restrict__ b1,
              const float* __restrict__ M2,   const float* __restrict__ P2,
              const float* __restrict__ g2,   const float* __restrict__ b2,
              float* __restrict__ out) {
    __shared__ __align__(16) float w[D_OUT * SPAD];
    __shared__ __align__(16) float xin[B_SZ * XPAD];
    __shared__ __align__(16) float xn [B_SZ * SPAD];
    __shared__ __align__(16) float x1b[B_SZ * SPAD];
    const int s = blockIdx.x, tid = threadIdx.x;
    const float sf = (float)s;

    for (int idx = tid; idx < B_SZ * D_IN; idx += NT_P) {
        int b = idx >> 6, k = idx & (D_IN - 1);
        xin[b * XPAD + k] = seq[(b * S_LEN + s) * D_IN + k];
    }
    for (int e = tid; e < NE; e += NT_P) {
        float pl[8];
        *(float4*)&pl[0] = *(const float4*)(P1 + e * NB);
        *(float4*)&pl[4] = *(const float4*)(P1 + e * NB + 4);
        float acc = 0.0f;
        #pragma unroll
        for (int g = 0; g < NB; ++g) {
            float v = sf * __builtin_amdgcn_rcpf((float)(e * NB + 2 + g));
            acc = fmaf(pl[g], cos_rev(v), acc);
        }
        int i = e / D_OUT;
        w[e + (SPAD - D_OUT) * i] = acc;
    }
    __syncthreads();
    for (int idx = tid; idx < B_SZ * D_OUT; idx += NT_P) {
        int i = idx >> 3, b = idx & 7;
        const float4* m  = (const float4*)(M1 + i * D_IN);
        const float4* wr = (const float4*)(Wres1 + i * D_IN);
        const float*  xr = xin + b * XPAD;
        float at = 0.0f, ar = 0.0f;
        #pragma unroll
        for (int k = 0; k < D_IN / 4; ++k) {
            float4 mv = m[k], rv = wr[k];
            float x0 = xr[4*k], x1 = xr[4*k+1], x2 = xr[4*k+2], x3 = xr[4*k+3];
            at = fmaf(mv.x, x0, fmaf(mv.y, x1, fmaf(mv.z, x2, fmaf(mv.w, x3, at))));
            ar = fmaf(rv.x, x0, fmaf(rv.y, x1, fmaf(rv.z, x2, fmaf(rv.w, x3, ar))));
        }
        xn [b * SPAD + i] = at;
        x1b[b * SPAD + i] = ar;
    }
    __syncthreads();
    {
        const int b = tid >> 5, rr = tid & 31;
        float* row = xn + b * SPAD;
        float v0 = row[rr], v1 = row[rr + 32], v2 = row[rr + 64];
        float sum = v0 + v1 + v2, sq = fmaf(v0, v0, fmaf(v1, v1, v2 * v2));
        #pragma unroll
        for (int off = 16; off > 0; off >>= 1) {
            sum += __shfl_down(sum, off, 32);
            sq  += __shfl_down(sq,  off, 32);
        }
        sum = __shfl(sum, 0, 32); sq = __shfl(sq, 0, 32);
        float mu = sum * (1.0f/96.0f), var = fmaf(sq, 1.0f/96.0f, -(mu*mu));
        float rs = rsqrtf(var + 1e-5f);
        row[rr]      = fmaf((v0 - mu) * rs, g1[rr],      b1[rr]);
        row[rr + 32] = fmaf((v1 - mu) * rs, g1[rr + 32], b1[rr + 32]);
        row[rr + 64] = fmaf((v2 - mu) * rs, g1[rr + 64], b1[rr + 64]);
    }
    __syncthreads();
    for (int idx = tid; idx < B_SZ * D_OUT; idx += NT_P) {
        int i = idx >> 3, b = idx & 7;
        const float* wrow = w + i * SPAD;
        const float* xr   = xn + b * SPAD;
        float acc = 0.0f;
        #pragma unroll
        for (int j = 0; j < D_OUT / 4; ++j) {
            float4 wv = *(const float4*)(wrow + 4 * j);
            float4 xv = *(const float4*)(xr + 4 * j);
            acc = fmaf(wv.x, xv.x, fmaf(wv.y, xv.y, fmaf(wv.z, xv.z, fmaf(wv.w, xv.w, acc))));
        }
        x1b[b * SPAD + i] += acc;
    }
    __syncthreads();
    for (int e = tid; e < NE; e += NT_P) {
        float pl[8];
        *(float4*)&pl[0] = *(const float4*)(P2 + e * NB);
        *(float4*)&pl[4] = *(const float4*)(P2 + e * NB + 4);
        float acc = 0.0f;
        #pragma unroll
        for (int g = 0; g < NB; ++g) {
            float v = sf * __builtin_amdgcn_rcpf((float)(e * NB + 2 + g));
            acc = fmaf(pl[g], cos_rev(v), acc);
        }
        int i = e / D_OUT;
        w[e + (SPAD - D_OUT) * i] = acc;
    }
    for (int idx = tid; idx < B_SZ * D_OUT; idx += NT_P) {
        int i = idx >> 3, b = idx & 7;
        const float4* m  = (const float4*)(M2 + i * D_OUT);
        const float*  xr = x1b + b * SPAD;
        float at = 0.0f;
        #pragma unroll
        for (int k = 0; k < D_OUT / 4; ++k) {
            float4 mv = m[k];
            at = fmaf(mv.x, xr[4*k], fmaf(mv.y, xr[4*k+1],
                 fmaf(mv.z, xr[4*k+2], fmaf(mv.w, xr[4*k+3], at))));
        }
        xn[b * SPAD + i] = at;
    }
    __syncthreads();
    {
        const int b = tid >> 5, rr = tid & 31;
        float* row = xn + b * SPAD;
        float v0 = row[rr], v1 = row[rr + 32], v2 = row[rr + 64];
        float sum = v0 + v1 + v2, sq = fmaf(v0, v0, fmaf(v1, v1, v2 * v2));
        #pragma unroll
        for (int off = 16; off > 0; off >>= 1) {
            sum += __shfl_down(sum, off, 32);
            sq  += __shfl_down(sq,  off, 32);
        }
        sum = __shfl(sum, 0, 32); sq = __shfl(sq, 0, 32);
        float mu = sum * (1.0f/96.0f), var = fmaf(sq, 1.0f/96.0f, -(mu*mu));
        float rs = rsqrtf(var + 1e-5f);
        row[rr]      = fmaf((v0 - mu) * rs, g2[rr],      b2[rr]);
        row[rr + 32] = fmaf((v1 - mu) * rs, g2[rr + 32], b2[rr + 32]);
        row[rr + 64] = fmaf((v2 - mu) * rs, g2[rr + 64], b2[rr + 64]);
    }
    __syncthreads();
    for (int idx = tid; idx < B_SZ * D_OUT; idx += NT_P) {
        int i = idx >> 3, b = idx & 7;
        const float* wrow = w + i * SPAD;
        const float* xr   = xn + b * SPAD;
        float acc = 0.0f;
        #pragma unroll
        for (int j = 0; j < D_OUT / 4; ++j) {
            float4 wv = *(const float4*)(wrow + 4 * j);
            float4 xv = *(const float4*)(xr + 4 * j);
            acc = fmaf(wv.x, xv.x, fmaf(wv.y, xv.y, fmaf(wv.z, xv.z, fmaf(wv.w, xv.w, acc))));
        }
        out[(b * S_LEN + s) * D_OUT + i] = acc + x1b[b * SPAD + i];
    }
}

extern "C" void kernel_launch(void* const* d_in, const int* in_sizes, int n_in,
                              void* d_out, int out_size, void* d_ws, size_t ws_size,
                              hipStream_t stream) {
    const float* seq   = (const float*)d_in[0];
    const float* M1    = (const float*)d_in[1];
    const float* P1    = (const float*)d_in[2];
    const float* Wres1 = (const float*)d_in[3];
    const float* g1    = (const float*)d_in[4];
    const float* b1    = (const float*)d_in[5];
    const float* M2    = (const float*)d_in[6];
    const float* P2    = (const float*)d_in[7];
    const float* g2    = (const float*)d_in[8];
    const float* b2    = (const float*)d_in[9];
    float* out = (float*)d_out;

    const size_t w_bytes  = (size_t)2 * S_LEN * NE * sizeof(__half);      // 37.75 MB
    const size_t xt_bytes = (size_t)NROWS * D_OUT * sizeof(float);        // 3.15 MB
    const size_t need     = w_bytes + 2 * xt_bytes;
    if (ws_size >= need) {
        __half* W1 = (__half*)d_ws;
        __half* W2 = W1 + (size_t)S_LEN * NE;
        float*  XT = (float*)((char*)d_ws + w_bytes);
        float*  RS = XT + (size_t)NROWS * D_OUT;
        producer<<<dim3(NWBLK + NGBLK), dim3(NT_P), 0, stream>>>(
            P1, P2, seq, M1, Wres1, W1, W2, XT, RS);
        consumer<<<dim3(S_LEN), dim3(NT_C), 0, stream>>>(
            XT, RS, M2, g1, b1, g2, b2, W1, W2, out);
    } else {
        hier_fallback<<<dim3(S_LEN), dim3(NT_P), 0, stream>>>(
            seq, M1, P1, Wres1, g1, b1, M2, P2, g2, b2, out);
    }
}